// Round 1
// baseline (416.744 us; speedup 1.0000x reference)
//
#include <hip/hip_runtime.h>

// ---------------------------------------------------------------------------
// VoxelTripletLoss — Round 3: pipelined gemm_big (counted vmcnt, T4) + NS=32.
// B=64, M=2048, FEAT=512, N=32768.
//
//   K1 prep:     V -> (v_hi, v_lo) bf16 in MFMA-frag-permuted layout, v_sq
//                partials, 1/||anchor||, 1/||key||
//   K2 gemm_big: dotp[ns][b][m] via mfma_f32_32x32x16_bf16 (v_hi*w + v_lo*w),
//                wsqp[ns][m] from the f32 W values during staging.
//                NEW: W f32 prefetch stays in flight across the barrier
//                (s_waitcnt vmcnt(4) + raw s_barrier, never vmcnt(0) in the
//                main loop), NS=32 -> 1024 blocks = 4 blocks/CU.
//   K3 keydist:  keyp[b][m] = anchor.keys^T (f32, K=512) + wsq reduce
//   K4 rowpart:  per (b, m-slice) hardest pos/neg partials
//   K5 final:    combine partials -> masked mean -> d_out[0]
// ---------------------------------------------------------------------------

typedef __attribute__((ext_vector_type(8)))  short bf16x8;
typedef __attribute__((ext_vector_type(16))) float f32x16;

constexpr int   Mdim   = 2048;
constexpr int   Nvox   = 32768;
constexpr int   NS     = 32;        // k-splits for big GEMM (32 -> 4 blocks/CU)
constexpr float BETA   = 0.8333333f;
constexpr float MARGIN = 0.2f;
constexpr float BIGV   = 1.0e9f;

// workspace layout (float offsets); total ~26 MB
constexpr size_t OFF_VSQP = 0;                       // 64*16
constexpr size_t OFF_AINV = 1024;                    // 64
constexpr size_t OFF_KINV = 1088;                    // 2048
constexpr size_t OFF_WSQ  = 3136;                    // 2048
constexpr size_t OFF_WSQP = 5184;                    // NS*2048 = 65536
constexpr size_t OFF_PHP  = 70720;                   // 256
constexpr size_t OFF_PHN  = 70976;                   // 256
constexpr size_t OFF_PAP  = 71232;                   // 256
constexpr size_t OFF_PAN  = 71488;                   // 256
constexpr size_t OFF_KEYP = 71744;                   // 64*2048 = 131072
constexpr size_t OFF_DOTP = 202816;                  // NS*64*2048 = 4194304
constexpr size_t OFF_VHI  = 4397120;                 // 2M ushort = 1048576 floats
constexpr size_t OFF_VLO  = 5445696;                 // 1048576 floats

__device__ __forceinline__ unsigned int bf16rne(float x) {
    unsigned int u = __float_as_uint(x);
    return (u + 0x7FFFu + ((u >> 16) & 1u)) >> 16;   // RNE to bf16, low 16 bits
}
__device__ __forceinline__ int pk2(unsigned int lo, unsigned int hi) {
    return (int)(lo | (hi << 16));                    // element k in low short
}
__device__ __forceinline__ void async16(const ushort* g, ushort* l) {
    __builtin_amdgcn_global_load_lds(
        (const __attribute__((address_space(1))) unsigned int*)g,
        (__attribute__((address_space(3))) unsigned int*)l, 16, 0, 0);
}

// ---------------------------------------------------------------------------
// K1 prep (unchanged from round 2).
// Blocks [0,256): V convert. 16 b-groups (4 rows) x 16 k-slices (2048 k).
//   frag-perm layout (ushort idx): chunk c=k>>6: c*4096 + (b>>5)*2048
//     + ((k>>4)&3)*512 + ((b&31) + 32*((k>>3)&1))*8 + (k&7)
// Blocks [256,784): feature-row norms (4 rows per block).
// ---------------------------------------------------------------------------
__global__ __launch_bounds__(256) void prep_kernel(
    const float* __restrict__ vox, const float* __restrict__ anc,
    const float* __restrict__ keys,
    ushort* __restrict__ vhi, ushort* __restrict__ vlo,
    float* __restrict__ vsqp, float* __restrict__ ainv, float* __restrict__ kinv)
{
    const int tid = threadIdx.x;
    if (blockIdx.x < 256) {
        const int bg = blockIdx.x >> 4;      // 0..15
        const int ks = blockIdx.x & 15;      // 0..15
        const int bsub = tid & 3;
        const int b  = bg * 4 + bsub;
        const int kw = tid >> 2;             // 0..63
        float sq = 0.f;
        #pragma unroll
        for (int it = 0; it < 2; ++it) {
            const int kloc = ks * 2048 + (it * 64 + kw) * 16;
            const float4* src = reinterpret_cast<const float4*>(vox + (size_t)b * Nvox + kloc);
            float4 x[4];
            #pragma unroll
            for (int j = 0; j < 4; ++j) x[j] = src[j];
            unsigned int h[16], l[16];
            #pragma unroll
            for (int j = 0; j < 4; ++j) {
                const float e[4] = {x[j].x, x[j].y, x[j].z, x[j].w};
                #pragma unroll
                for (int q = 0; q < 4; ++q) {
                    const float v = e[q];
                    sq = fmaf(v, v, sq);
                    const unsigned int hb = bf16rne(v);
                    h[j*4+q] = hb;
                    const float r = v - __uint_as_float(hb << 16);
                    l[j*4+q] = bf16rne(r);
                }
            }
            const int c = kloc >> 6, s = (kloc >> 4) & 3;
            const size_t base = (size_t)c * 4096 + (b >> 5) * 2048 + s * 512 + (b & 31) * 8;
            int4 hp0 = { pk2(h[0],h[1]), pk2(h[2],h[3]), pk2(h[4],h[5]), pk2(h[6],h[7]) };
            int4 hp1 = { pk2(h[8],h[9]), pk2(h[10],h[11]), pk2(h[12],h[13]), pk2(h[14],h[15]) };
            int4 lp0 = { pk2(l[0],l[1]), pk2(l[2],l[3]), pk2(l[4],l[5]), pk2(l[6],l[7]) };
            int4 lp1 = { pk2(l[8],l[9]), pk2(l[10],l[11]), pk2(l[12],l[13]), pk2(l[14],l[15]) };
            *reinterpret_cast<int4*>(vhi + base)       = hp0;
            *reinterpret_cast<int4*>(vhi + base + 256) = hp1;
            *reinterpret_cast<int4*>(vlo + base)       = lp0;
            *reinterpret_cast<int4*>(vlo + base + 256) = lp1;
        }
        #pragma unroll
        for (int off = 32; off >= 4; off >>= 1) sq += __shfl_down(sq, off);
        __shared__ float red[16];
        const int lane = tid & 63, wave = tid >> 6;
        if (lane < 4) red[wave * 4 + lane] = sq;
        __syncthreads();
        if (tid < 4)
            vsqp[(size_t)(bg * 4 + tid) * 16 + ks] =
                red[tid] + red[tid + 4] + red[tid + 8] + red[tid + 12];
    } else {
        const int r = (blockIdx.x - 256) * 4 + (tid >> 6);   // 0..2111
        const int lane = tid & 63;
        const float* src = (r < 64) ? (anc + (size_t)r * 512)
                                    : (keys + (size_t)(r - 64) * 512);
        const float4* s4 = reinterpret_cast<const float4*>(src);
        float4 x = s4[lane];
        float4 y = s4[lane + 64];
        float p = 0.f;
        p = fmaf(x.x, x.x, p); p = fmaf(x.y, x.y, p);
        p = fmaf(x.z, x.z, p); p = fmaf(x.w, x.w, p);
        p = fmaf(y.x, y.x, p); p = fmaf(y.y, y.y, p);
        p = fmaf(y.z, y.z, p); p = fmaf(y.w, y.w, p);
        #pragma unroll
        for (int off = 32; off > 0; off >>= 1) p += __shfl_down(p, off);
        if (lane == 0) {
            float inv = 1.f / fmaxf(sqrtf(p), 1e-8f);
            if (r < 64) ainv[r] = inv; else kinv[r - 64] = inv;
        }
    }
}

// ---------------------------------------------------------------------------
// K2: dotp[ns][64][2048] via MFMA. Block = 64 b x 64 m, 4 waves as 2x2 of
// 32x32 tiles. NS=32 -> 1024 blocks, 16 chunks of 64 k per block.
// Pipeline per chunk (T4 counted waits, never vmcnt(0) in main loop):
//   convert wreg (W ch, loaded one chunk ago; compiler vmcnt-waits it here)
//   __syncthreads()                    // B1 — free: vmcnt already 0
//   async V(ch)->LDS ×4, ds_write W(ch) bf16, then prefetch W(ch+1) f32
//   s_waitcnt vmcnt(4) lgkmcnt(0)      // V asyncs (oldest 4) done; W(ch+1)
//   s_barrier; sched_barrier(0)        //   stays in flight across barrier
//   8 MFMAs on chunk ch
// ---------------------------------------------------------------------------
__global__ __launch_bounds__(256, 4) void gemm_big(
    const ushort* __restrict__ vhi, const ushort* __restrict__ vlo,
    const float* __restrict__ W,
    float* __restrict__ dotp, float* __restrict__ wsqp)
{
    __shared__ ushort sVhi[4096], sVlo[4096], sWhi[4096];   // 8 KB each
    __shared__ float red[256];

    const int tid  = threadIdx.x;
    const int lane = tid & 63;
    const int wave = tid >> 6;
    const int mb   = blockIdx.x & 31;       // m-block 0..31
    const int ns   = blockIdx.x >> 5;       // k-split 0..31
    const int srow = tid >> 2;              // staged W row 0..63
    const int sq   = tid & 3;               // k-step within chunk

    const float*  wptr = W + (size_t)(mb * 64 + srow) * Nvox + ns * 1024 + sq * 16;
    const ushort* vhig = vhi + (size_t)(ns * 16) * 4096 + wave * 1024 + lane * 8;
    const ushort* vlog = vlo + (size_t)(ns * 16) * 4096 + wave * 1024 + lane * 8;
    ushort* ldsVhi = &sVhi[wave * 1024];    // lane-uniform DMA dest
    ushort* ldsVlo = &sVlo[wave * 1024];

    const int wr = wave >> 1, wc = wave & 1;
    f32x16 acc = {};
    float wsq = 0.f;

    float4 wreg[4];
    #pragma unroll
    for (int j = 0; j < 4; ++j) wreg[j] = *reinterpret_cast<const float4*>(wptr + j * 4);

    const int woff0 = (srow >> 5) * 2048 + sq * 512 + (srow & 31) * 8;

    for (int ch = 0; ch < 16; ++ch) {
        // convert W chunk (in regs since last iteration), f32 sum of squares
        int4 p0, p1;
        {
            unsigned int hb[16];
            #pragma unroll
            for (int j = 0; j < 4; ++j) {
                const float e[4] = {wreg[j].x, wreg[j].y, wreg[j].z, wreg[j].w};
                #pragma unroll
                for (int q = 0; q < 4; ++q) {
                    wsq = fmaf(e[q], e[q], wsq);
                    hb[j*4+q] = bf16rne(e[q]);
                }
            }
            p0 = (int4){ pk2(hb[0],hb[1]), pk2(hb[2],hb[3]), pk2(hb[4],hb[5]), pk2(hb[6],hb[7]) };
            p1 = (int4){ pk2(hb[8],hb[9]), pk2(hb[10],hb[11]), pk2(hb[12],hb[13]), pk2(hb[14],hb[15]) };
        }
        // B1: all waves done reading previous chunk's LDS. vmcnt is already 0
        // (wreg fully consumed above), so the implicit drain costs nothing.
        __syncthreads();
        // async V hi/lo -> LDS (each wave: its 2 KB quarter, 1 KB per instr)
        async16(vhig + (size_t)ch * 4096,       ldsVhi);
        async16(vhig + (size_t)ch * 4096 + 512, ldsVhi + 512);
        async16(vlog + (size_t)ch * 4096,       ldsVlo);
        async16(vlog + (size_t)ch * 4096 + 512, ldsVlo + 512);
        // W bf16 -> LDS frag order
        *reinterpret_cast<int4*>(&sWhi[woff0])       = p0;
        *reinterpret_cast<int4*>(&sWhi[woff0 + 256]) = p1;
        // pin issue order: the 4 V asyncs above must be OLDER than the W
        // prefetch below, so vmcnt(4) means "V asyncs complete".
        asm volatile("" ::: "memory");
        if (ch != 15) {
            #pragma unroll
            for (int j = 0; j < 4; ++j)
                wreg[j] = *reinterpret_cast<const float4*>(wptr + (ch + 1) * 64 + j * 4);
            // drain the V DMAs + LDS writes, keep W(ch+1) in flight
            asm volatile("s_waitcnt vmcnt(4) lgkmcnt(0)" ::: "memory");
        } else {
            asm volatile("s_waitcnt vmcnt(0) lgkmcnt(0)" ::: "memory");
        }
        __builtin_amdgcn_s_barrier();                 // B2
        __builtin_amdgcn_sched_barrier(0);            // frag reads stay below
        #pragma unroll
        for (int s = 0; s < 4; ++s) {
            bf16x8 ah = *reinterpret_cast<const bf16x8*>(&sVhi[wr * 2048 + s * 512 + lane * 8]);
            bf16x8 al = *reinterpret_cast<const bf16x8*>(&sVlo[wr * 2048 + s * 512 + lane * 8]);
            bf16x8 bh = *reinterpret_cast<const bf16x8*>(&sWhi[wc * 2048 + s * 512 + lane * 8]);
            acc = __builtin_amdgcn_mfma_f32_32x32x16_bf16(ah, bh, acc, 0, 0, 0);
            acc = __builtin_amdgcn_mfma_f32_32x32x16_bf16(al, bh, acc, 0, 0, 0);
        }
    }

    // epilogue: C layout col=lane&31, row=(reg&3)+8*(reg>>2)+4*(lane>>5)
    const int col   = lane & 31;
    const int rbase = 4 * (lane >> 5);
    const size_t out_m = (size_t)(mb * 64 + wc * 32 + col);
    #pragma unroll
    for (int r = 0; r < 16; ++r) {
        const int row = (r & 3) + 8 * (r >> 2) + rbase;
        const int b   = wr * 32 + row;
        dotp[(size_t)(ns * 64 + b) * Mdim + out_m] = acc[r];
    }
    red[tid] = wsq;
    __syncthreads();
    if (tid < 64)
        wsqp[(size_t)ns * Mdim + mb * 64 + tid] =
            red[tid*4] + red[tid*4+1] + red[tid*4+2] + red[tid*4+3];
}

// ---------------------------------------------------------------------------
// K3: blocks [0,256): key dots (8 m-rows per block, keys staged in LDS);
//     blocks [256,264): wsq[m] = sum_s wsqp[s][m]
// ---------------------------------------------------------------------------
__global__ __launch_bounds__(256) void keydist_kernel(
    const float* __restrict__ anc, const float* __restrict__ keys,
    const float* __restrict__ wsqp, float* __restrict__ keyp,
    float* __restrict__ wsq)
{
    const int tid = threadIdx.x;
    if (blockIdx.x >= 256) {
        const int m = (blockIdx.x - 256) * 256 + tid;
        float s = 0.f;
        #pragma unroll
        for (int sp = 0; sp < NS; ++sp) s += wsqp[(size_t)sp * Mdim + m];
        wsq[m] = s;
        return;
    }
    __shared__ float kk[8 * 516];
    const int mt = blockIdx.x * 8;
    {
        const int row = tid >> 5, colb = (tid & 31) * 16;
        const float4* src = reinterpret_cast<const float4*>(keys + (size_t)(mt + row) * 512 + colb);
        #pragma unroll
        for (int j = 0; j < 4; ++j)
            *reinterpret_cast<float4*>(&kk[row * 516 + colb + j * 4]) = src[j];
    }
    __syncthreads();
    const int b = tid >> 2, msub = tid & 3;
    const float* arow = anc + (size_t)b * 512;
    const float* k0 = &kk[msub * 516];
    const float* k1 = &kk[(msub + 4) * 516];
    float d0 = 0.f, d1 = 0.f;
    #pragma unroll 4
    for (int k = 0; k < 512; k += 4) {
        const float4 a = *reinterpret_cast<const float4*>(arow + k);
        const float4 x = *reinterpret_cast<const float4*>(k0 + k);
        const float4 y = *reinterpret_cast<const float4*>(k1 + k);
        d0 = fmaf(a.x, x.x, d0); d0 = fmaf(a.y, x.y, d0);
        d0 = fmaf(a.z, x.z, d0); d0 = fmaf(a.w, x.w, d0);
        d1 = fmaf(a.x, y.x, d1); d1 = fmaf(a.y, y.y, d1);
        d1 = fmaf(a.z, y.z, d1); d1 = fmaf(a.w, y.w, d1);
    }
    keyp[(size_t)b * Mdim + mt + msub]     = d0;
    keyp[(size_t)b * Mdim + mt + msub + 4] = d1;
}

// ---------------------------------------------------------------------------
// K4: grid 256 = 64 b x 4 m-slices (512 m each): partial hardest pos/neg
// ---------------------------------------------------------------------------
__global__ __launch_bounds__(256) void rowpart_kernel(
    const float* __restrict__ dotp, const float* __restrict__ wsq,
    const float* __restrict__ keyp, const float* __restrict__ vsqp,
    const float* __restrict__ ainv, const float* __restrict__ kinv,
    float* __restrict__ php, float* __restrict__ phn,
    float* __restrict__ pap, float* __restrict__ pan)
{
    const int bid = blockIdx.x, tid = threadIdx.x;
    const int b = bid >> 2, sl = bid & 3;
    float vs = 0.f;
    #pragma unroll
    for (int i = 0; i < 16; ++i) vs += vsqp[(size_t)b * 16 + i];
    const float ai = ainv[b];
    float hp = -BIGV, hn = BIGV, ap = 0.f, an = 0.f;
    #pragma unroll
    for (int rep = 0; rep < 2; ++rep) {
        const int m = sl * 512 + rep * 256 + tid;
        float dot = 0.f;
        #pragma unroll
        for (int s = 0; s < NS; ++s) dot += dotp[(size_t)(s * 64 + b) * Mdim + m];
        const float sv = 1.f - (vs + wsq[m] - 2.f * dot) * (1.f / 32768.f);
        const float kd = 1.f - keyp[(size_t)b * Mdim + m] * ai * kinv[m];
        if (sv > BETA) { ap = 1.f; hp = fmaxf(hp, kd); }
        if (sv < BETA) { an = 1.f; hn = fminf(hn, kd); }
    }
    #pragma unroll
    for (int off = 32; off > 0; off >>= 1) {
        hp = fmaxf(hp, __shfl_down(hp, off));
        hn = fminf(hn, __shfl_down(hn, off));
        ap = fmaxf(ap, __shfl_down(ap, off));
        an = fmaxf(an, __shfl_down(an, off));
    }
    __shared__ float sb[16];
    const int wv = tid >> 6;
    if ((tid & 63) == 0) {
        sb[wv * 4 + 0] = hp; sb[wv * 4 + 1] = hn;
        sb[wv * 4 + 2] = ap; sb[wv * 4 + 3] = an;
    }
    __syncthreads();
    if (tid == 0) {
        for (int w2 = 1; w2 < 4; ++w2) {
            hp = fmaxf(hp, sb[w2 * 4 + 0]);
            hn = fminf(hn, sb[w2 * 4 + 1]);
            ap = fmaxf(ap, sb[w2 * 4 + 2]);
            an = fmaxf(an, sb[w2 * 4 + 3]);
        }
        php[bid] = hp; phn[bid] = hn; pap[bid] = ap; pan[bid] = an;
    }
}

// ---------------------------------------------------------------------------
// K5: single block: combine 4 partials per b -> loss/valid -> masked mean
// ---------------------------------------------------------------------------
__global__ void final_kernel(const float* __restrict__ php, const float* __restrict__ phn,
                             const float* __restrict__ pap, const float* __restrict__ pan,
                             float* __restrict__ out)
{
    const int t = threadIdx.x;   // 256
    float hp = php[t], hn = phn[t], ap = pap[t], an = pan[t];
    hp = fmaxf(hp, __shfl_down(hp, 2)); hp = fmaxf(hp, __shfl_down(hp, 1));
    hn = fminf(hn, __shfl_down(hn, 2)); hn = fminf(hn, __shfl_down(hn, 1));
    ap = fmaxf(ap, __shfl_down(ap, 2)); ap = fmaxf(ap, __shfl_down(ap, 1));
    an = fmaxf(an, __shfl_down(an, 2)); an = fmaxf(an, __shfl_down(an, 1));
    __shared__ float sl[64], sc[64];
    if ((t & 3) == 0) {
        const int b = t >> 2;
        const float valid = (ap > 0.f && an > 0.f) ? 1.f : 0.f;
        sl[b] = fmaxf(hp - hn + MARGIN, 0.f) * valid;
        sc[b] = valid;
    }
    __syncthreads();
    if (t < 64) {
        float l = sl[t], c = sc[t];
        #pragma unroll
        for (int off = 32; off > 0; off >>= 1) {
            l += __shfl_down(l, off);
            c += __shfl_down(c, off);
        }
        if (t == 0) out[0] = (c > 0.f) ? (l / c) : 0.f;
    }
}

// ---------------------------------------------------------------------------
extern "C" void kernel_launch(void* const* d_in, const int* in_sizes, int n_in,
                              void* d_out, int out_size, void* d_ws, size_t ws_size,
                              hipStream_t stream) {
    const float* anchor = (const float*)d_in[0];   // (64, 512)
    const float* voxels = (const float*)d_in[1];   // (64, 32768)
    const float* keys   = (const float*)d_in[2];   // (2048, 512)
    const float* vals   = (const float*)d_in[3];   // (2048, 32768)

    float* ws = (float*)d_ws;
    float*  vsqp = ws + OFF_VSQP;
    float*  ainv = ws + OFF_AINV;
    float*  kinv = ws + OFF_KINV;
    float*  wsq  = ws + OFF_WSQ;
    float*  wsqp = ws + OFF_WSQP;
    float*  php  = ws + OFF_PHP;
    float*  phn  = ws + OFF_PHN;
    float*  pap  = ws + OFF_PAP;
    float*  pan  = ws + OFF_PAN;
    float*  keyp = ws + OFF_KEYP;
    float*  dotp = ws + OFF_DOTP;
    ushort* vhi  = (ushort*)(ws + OFF_VHI);
    ushort* vlo  = (ushort*)(ws + OFF_VLO);

    prep_kernel<<<784, 256, 0, stream>>>(voxels, anchor, keys, vhi, vlo, vsqp, ainv, kinv);
    gemm_big<<<32 * NS, 256, 0, stream>>>(vhi, vlo, vals, dotp, wsqp);
    keydist_kernel<<<264, 256, 0, stream>>>(anchor, keys, wsqp, keyp, wsq);
    rowpart_kernel<<<256, 256, 0, stream>>>(dotp, wsq, keyp, vsqp, ainv, kinv,
                                            php, phn, pap, pan);
    final_kernel<<<1, 256, 0, stream>>>(php, phn, pap, pan, (float*)d_out);
}

// Round 2
// 407.452 us; speedup vs baseline: 1.0228x; 1.0228x over previous
//
#include <hip/hip_runtime.h>

// ---------------------------------------------------------------------------
// VoxelTripletLoss — Round 4: 3-dispatch pipeline (fused launches).
// B=64, M=2048, FEAT=512, N=32768.
//
//   K1 prep:     blocks [0,256)    V -> (v_hi, v_lo) bf16 frag-perm + v_sq
//                blocks [256,784)  1/||anchor||, 1/||key||
//                blocks [784,1040) keyp[b][m] = anchor.keys^T (f32, K=512)
//                (+ block 0 zeroes the rowpart ticket counter)
//   K2 gemm_big: dotp[ns][b][m] via mfma_f32_32x32x16_bf16 (v_hi*w + v_lo*w),
//                wsqp[ns][m] from the f32 W values during staging. NS=16.
//                (round-0 structure: memory-bound at ~285 MB, MFMA is 7 us)
//   K3 rowpart:  per (b, m-slice) hardest pos/neg partials, wsq summed
//                inline from wsqp; last block (atomic ticket) combines
//                partials -> masked mean -> d_out[0].
// ---------------------------------------------------------------------------

typedef __attribute__((ext_vector_type(8)))  short bf16x8;
typedef __attribute__((ext_vector_type(16))) float f32x16;

constexpr int   Mdim   = 2048;
constexpr int   Nvox   = 32768;
constexpr int   NS     = 16;        // k-splits for big GEMM
constexpr float BETA   = 0.8333333f;
constexpr float MARGIN = 0.2f;
constexpr float BIGV   = 1.0e9f;

// workspace layout (float offsets); total ~17.5 MB
constexpr size_t OFF_VSQP = 0;                       // 64*16
constexpr size_t OFF_AINV = 1024;                    // 64
constexpr size_t OFF_KINV = 1088;                    // 2048
constexpr size_t OFF_WSQP = 3136;                    // NS*2048 = 32768
constexpr size_t OFF_PHP  = 35904;                   // 256
constexpr size_t OFF_PHN  = 36160;                   // 256
constexpr size_t OFF_PAP  = 36416;                   // 256
constexpr size_t OFF_PAN  = 36672;                   // 256
constexpr size_t OFF_CNT  = 36928;                   // 64 (ticket counter)
constexpr size_t OFF_KEYP = 36992;                   // 64*2048 = 131072
constexpr size_t OFF_DOTP = 168064;                  // NS*64*2048 = 2097152
constexpr size_t OFF_VHI  = 2265216;                 // 2M ushort = 1048576 floats
constexpr size_t OFF_VLO  = 3313792;                 // 1048576 floats

__device__ __forceinline__ unsigned int bf16rne(float x) {
    unsigned int u = __float_as_uint(x);
    return (u + 0x7FFFu + ((u >> 16) & 1u)) >> 16;   // RNE to bf16, low 16 bits
}
__device__ __forceinline__ int pk2(unsigned int lo, unsigned int hi) {
    return (int)(lo | (hi << 16));                    // element k in low short
}
__device__ __forceinline__ void async16(const ushort* g, ushort* l) {
    __builtin_amdgcn_global_load_lds(
        (const __attribute__((address_space(1))) unsigned int*)g,
        (__attribute__((address_space(3))) unsigned int*)l, 16, 0, 0);
}

// ---------------------------------------------------------------------------
// K1 prep (three independent block ranges fused into one dispatch).
// Blocks [0,256): V convert. 16 b-groups (4 rows) x 16 k-slices (2048 k).
//   frag-perm layout (ushort idx): chunk c=k>>6: c*4096 + (b>>5)*2048
//     + ((k>>4)&3)*512 + ((b&31) + 32*((k>>3)&1))*8 + (k&7)
// Blocks [256,784): feature-row norms (4 rows per block).
// Blocks [784,1040): key-dot rows (8 m-rows per block, keys staged in LDS).
// ---------------------------------------------------------------------------
__global__ __launch_bounds__(256) void prep_kernel(
    const float* __restrict__ vox, const float* __restrict__ anc,
    const float* __restrict__ keys,
    ushort* __restrict__ vhi, ushort* __restrict__ vlo,
    float* __restrict__ vsqp, float* __restrict__ ainv, float* __restrict__ kinv,
    float* __restrict__ keyp, int* __restrict__ cnt)
{
    __shared__ float kk[8 * 516];          // keydist staging (also covers red[])
    const int tid = threadIdx.x;
    if (blockIdx.x < 256) {
        if (blockIdx.x == 0 && tid == 0) cnt[0] = 0;   // rowpart ticket
        const int bg = blockIdx.x >> 4;      // 0..15
        const int ks = blockIdx.x & 15;      // 0..15
        const int bsub = tid & 3;
        const int b  = bg * 4 + bsub;
        const int kw = tid >> 2;             // 0..63
        float sq = 0.f;
        #pragma unroll
        for (int it = 0; it < 2; ++it) {
            const int kloc = ks * 2048 + (it * 64 + kw) * 16;
            const float4* src = reinterpret_cast<const float4*>(vox + (size_t)b * Nvox + kloc);
            float4 x[4];
            #pragma unroll
            for (int j = 0; j < 4; ++j) x[j] = src[j];
            unsigned int h[16], l[16];
            #pragma unroll
            for (int j = 0; j < 4; ++j) {
                const float e[4] = {x[j].x, x[j].y, x[j].z, x[j].w};
                #pragma unroll
                for (int q = 0; q < 4; ++q) {
                    const float v = e[q];
                    sq = fmaf(v, v, sq);
                    const unsigned int hb = bf16rne(v);
                    h[j*4+q] = hb;
                    const float r = v - __uint_as_float(hb << 16);
                    l[j*4+q] = bf16rne(r);
                }
            }
            const int c = kloc >> 6, s = (kloc >> 4) & 3;
            const size_t base = (size_t)c * 4096 + (b >> 5) * 2048 + s * 512 + (b & 31) * 8;
            int4 hp0 = { pk2(h[0],h[1]), pk2(h[2],h[3]), pk2(h[4],h[5]), pk2(h[6],h[7]) };
            int4 hp1 = { pk2(h[8],h[9]), pk2(h[10],h[11]), pk2(h[12],h[13]), pk2(h[14],h[15]) };
            int4 lp0 = { pk2(l[0],l[1]), pk2(l[2],l[3]), pk2(l[4],l[5]), pk2(l[6],l[7]) };
            int4 lp1 = { pk2(l[8],l[9]), pk2(l[10],l[11]), pk2(l[12],l[13]), pk2(l[14],l[15]) };
            *reinterpret_cast<int4*>(vhi + base)       = hp0;
            *reinterpret_cast<int4*>(vhi + base + 256) = hp1;
            *reinterpret_cast<int4*>(vlo + base)       = lp0;
            *reinterpret_cast<int4*>(vlo + base + 256) = lp1;
        }
        #pragma unroll
        for (int off = 32; off >= 4; off >>= 1) sq += __shfl_down(sq, off);
        const int lane = tid & 63, wave = tid >> 6;
        if (lane < 4) kk[wave * 4 + lane] = sq;
        __syncthreads();
        if (tid < 4)
            vsqp[(size_t)(bg * 4 + tid) * 16 + ks] =
                kk[tid] + kk[tid + 4] + kk[tid + 8] + kk[tid + 12];
    } else if (blockIdx.x < 784) {
        const int r = (blockIdx.x - 256) * 4 + (tid >> 6);   // 0..2111
        const int lane = tid & 63;
        const float* src = (r < 64) ? (anc + (size_t)r * 512)
                                    : (keys + (size_t)(r - 64) * 512);
        const float4* s4 = reinterpret_cast<const float4*>(src);
        float4 x = s4[lane];
        float4 y = s4[lane + 64];
        float p = 0.f;
        p = fmaf(x.x, x.x, p); p = fmaf(x.y, x.y, p);
        p = fmaf(x.z, x.z, p); p = fmaf(x.w, x.w, p);
        p = fmaf(y.x, y.x, p); p = fmaf(y.y, y.y, p);
        p = fmaf(y.z, y.z, p); p = fmaf(y.w, y.w, p);
        #pragma unroll
        for (int off = 32; off > 0; off >>= 1) p += __shfl_down(p, off);
        if (lane == 0) {
            float inv = 1.f / fmaxf(sqrtf(p), 1e-8f);
            if (r < 64) ainv[r] = inv; else kinv[r - 64] = inv;
        }
    } else {
        // key-dot rows: 8 m-rows per block, all 64 anchors
        const int mt = (blockIdx.x - 784) * 8;
        {
            const int row = tid >> 5, colb = (tid & 31) * 16;
            const float4* src = reinterpret_cast<const float4*>(keys + (size_t)(mt + row) * 512 + colb);
            #pragma unroll
            for (int j = 0; j < 4; ++j)
                *reinterpret_cast<float4*>(&kk[row * 516 + colb + j * 4]) = src[j];
        }
        __syncthreads();
        const int b = tid >> 2, msub = tid & 3;
        const float* arow = anc + (size_t)b * 512;
        const float* k0 = &kk[msub * 516];
        const float* k1 = &kk[(msub + 4) * 516];
        float d0 = 0.f, d1 = 0.f;
        #pragma unroll 4
        for (int k = 0; k < 512; k += 4) {
            const float4 a = *reinterpret_cast<const float4*>(arow + k);
            const float4 x = *reinterpret_cast<const float4*>(k0 + k);
            const float4 y = *reinterpret_cast<const float4*>(k1 + k);
            d0 = fmaf(a.x, x.x, d0); d0 = fmaf(a.y, x.y, d0);
            d0 = fmaf(a.z, x.z, d0); d0 = fmaf(a.w, x.w, d0);
            d1 = fmaf(a.x, y.x, d1); d1 = fmaf(a.y, y.y, d1);
            d1 = fmaf(a.z, y.z, d1); d1 = fmaf(a.w, y.w, d1);
        }
        keyp[(size_t)b * Mdim + mt + msub]     = d0;
        keyp[(size_t)b * Mdim + mt + msub + 4] = d1;
    }
}

// ---------------------------------------------------------------------------
// K2: dotp[ns][64][2048] via MFMA. Block = 64 b x 64 m, 4 waves as 2x2 of
// 32x32 tiles. Per 64-k chunk: V hi/lo via global_load_lds (frag order),
// W loaded f32 (register-prefetched), converted to bf16, ds_written in frag
// order. 2 MFMAs per k-step: acc += vhi*w; acc += vlo*w.
// Memory-bound (285 MB vs 7 us of MFMA) — round-0 structure, NS=16.
// ---------------------------------------------------------------------------
__global__ __launch_bounds__(256) void gemm_big(
    const ushort* __restrict__ vhi, const ushort* __restrict__ vlo,
    const float* __restrict__ W,
    float* __restrict__ dotp, float* __restrict__ wsqp)
{
    __shared__ ushort sVhi[4096], sVlo[4096], sWhi[4096];   // 8 KB each
    __shared__ float red[256];

    const int tid  = threadIdx.x;
    const int lane = tid & 63;
    const int wave = tid >> 6;
    const int mb   = blockIdx.x & 31;       // m-block
    const int ns   = blockIdx.x >> 5;       // k-split
    const int srow = tid >> 2;              // staged W row 0..63
    const int sq   = tid & 3;               // k-step within chunk

    const float*  wptr = W + (size_t)(mb * 64 + srow) * Nvox + ns * 2048 + sq * 16;
    const ushort* vhig = vhi + (size_t)(ns * 32) * 4096 + wave * 1024 + lane * 8;
    const ushort* vlog = vlo + (size_t)(ns * 32) * 4096 + wave * 1024 + lane * 8;
    ushort* ldsVhi = &sVhi[wave * 1024];    // lane-uniform DMA dest
    ushort* ldsVlo = &sVlo[wave * 1024];

    const int wr = wave >> 1, wc = wave & 1;
    f32x16 acc = {};
    float wsq = 0.f;

    float4 wreg[4];
    #pragma unroll
    for (int j = 0; j < 4; ++j) wreg[j] = *reinterpret_cast<const float4*>(wptr + j * 4);

    const int woff0 = (srow >> 5) * 2048 + sq * 512 + (srow & 31) * 8;

    for (int ch = 0; ch < 32; ++ch) {
        // convert W chunk (already in regs), accumulate f32 sum of squares
        int4 p0, p1;
        {
            unsigned int hb[16];
            #pragma unroll
            for (int j = 0; j < 4; ++j) {
                const float e[4] = {wreg[j].x, wreg[j].y, wreg[j].z, wreg[j].w};
                #pragma unroll
                for (int q = 0; q < 4; ++q) {
                    wsq = fmaf(e[q], e[q], wsq);
                    hb[j*4+q] = bf16rne(e[q]);
                }
            }
            p0 = (int4){ pk2(hb[0],hb[1]), pk2(hb[2],hb[3]), pk2(hb[4],hb[5]), pk2(hb[6],hb[7]) };
            p1 = (int4){ pk2(hb[8],hb[9]), pk2(hb[10],hb[11]), pk2(hb[12],hb[13]), pk2(hb[14],hb[15]) };
        }
        __syncthreads();                     // all waves done reading prev chunk
        // async V hi/lo -> LDS (each wave: its 2 KB quarter, 1 KB per instr)
        async16(vhig + (size_t)ch * 4096,       ldsVhi);
        async16(vhig + (size_t)ch * 4096 + 512, ldsVhi + 512);
        async16(vlog + (size_t)ch * 4096,       ldsVlo);
        async16(vlog + (size_t)ch * 4096 + 512, ldsVlo + 512);
        // W bf16 -> LDS frag order
        *reinterpret_cast<int4*>(&sWhi[woff0])       = p0;
        *reinterpret_cast<int4*>(&sWhi[woff0 + 256]) = p1;
        // prefetch next W chunk (drained by barrier2's vmcnt wait)
        if (ch < 31) {
            #pragma unroll
            for (int j = 0; j < 4; ++j)
                wreg[j] = *reinterpret_cast<const float4*>(wptr + (ch + 1) * 64 + j * 4);
        }
        __syncthreads();                     // V DMA + W writes visible
        #pragma unroll
        for (int s = 0; s < 4; ++s) {
            bf16x8 ah = *reinterpret_cast<const bf16x8*>(&sVhi[wr * 2048 + s * 512 + lane * 8]);
            bf16x8 al = *reinterpret_cast<const bf16x8*>(&sVlo[wr * 2048 + s * 512 + lane * 8]);
            bf16x8 bh = *reinterpret_cast<const bf16x8*>(&sWhi[wc * 2048 + s * 512 + lane * 8]);
            acc = __builtin_amdgcn_mfma_f32_32x32x16_bf16(ah, bh, acc, 0, 0, 0);
            acc = __builtin_amdgcn_mfma_f32_32x32x16_bf16(al, bh, acc, 0, 0, 0);
        }
    }

    // epilogue: C layout col=lane&31, row=(reg&3)+8*(reg>>2)+4*(lane>>5)
    const int col   = lane & 31;
    const int rbase = 4 * (lane >> 5);
    const size_t out_m = (size_t)(mb * 64 + wc * 32 + col);
    #pragma unroll
    for (int r = 0; r < 16; ++r) {
        const int row = (r & 3) + 8 * (r >> 2) + rbase;
        const int b   = wr * 32 + row;
        dotp[(size_t)(ns * 64 + b) * Mdim + out_m] = acc[r];
    }
    red[tid] = wsq;
    __syncthreads();
    if (tid < 64)
        wsqp[(size_t)ns * Mdim + mb * 64 + tid] =
            red[tid*4] + red[tid*4+1] + red[tid*4+2] + red[tid*4+3];
}

// ---------------------------------------------------------------------------
// K3: grid 256 = 64 b x 4 m-slices (512 m each): partial hardest pos/neg,
// wsq[m] summed inline from wsqp. Last block (device-scope atomic ticket)
// combines the 256 partials -> masked mean -> out[0].
// ---------------------------------------------------------------------------
__global__ __launch_bounds__(256) void rowpart_kernel(
    const float* __restrict__ dotp, const float* __restrict__ wsqp,
    const float* __restrict__ keyp, const float* __restrict__ vsqp,
    const float* __restrict__ ainv, const float* __restrict__ kinv,
    float* __restrict__ php, float* __restrict__ phn,
    float* __restrict__ pap, float* __restrict__ pan,
    int* __restrict__ cnt, float* __restrict__ out)
{
    const int bid = blockIdx.x, tid = threadIdx.x;
    const int b = bid >> 2, slc = bid & 3;
    float vs = 0.f;
    #pragma unroll
    for (int i = 0; i < 16; ++i) vs += vsqp[(size_t)b * 16 + i];
    const float ai = ainv[b];
    float hp = -BIGV, hn = BIGV, ap = 0.f, an = 0.f;
    #pragma unroll
    for (int rep = 0; rep < 2; ++rep) {
        const int m = slc * 512 + rep * 256 + tid;
        float dot = 0.f, wq = 0.f;
        #pragma unroll
        for (int s = 0; s < NS; ++s) {
            dot += dotp[(size_t)(s * 64 + b) * Mdim + m];
            wq  += wsqp[(size_t)s * Mdim + m];
        }
        const float sv = 1.f - (vs + wq - 2.f * dot) * (1.f / 32768.f);
        const float kd = 1.f - keyp[(size_t)b * Mdim + m] * ai * kinv[m];
        if (sv > BETA) { ap = 1.f; hp = fmaxf(hp, kd); }
        if (sv < BETA) { an = 1.f; hn = fminf(hn, kd); }
    }
    #pragma unroll
    for (int off = 32; off > 0; off >>= 1) {
        hp = fmaxf(hp, __shfl_down(hp, off));
        hn = fminf(hn, __shfl_down(hn, off));
        ap = fmaxf(ap, __shfl_down(ap, off));
        an = fmaxf(an, __shfl_down(an, off));
    }
    __shared__ float sb[16];
    __shared__ int isLast;
    const int wv = tid >> 6;
    if ((tid & 63) == 0) {
        sb[wv * 4 + 0] = hp; sb[wv * 4 + 1] = hn;
        sb[wv * 4 + 2] = ap; sb[wv * 4 + 3] = an;
    }
    __syncthreads();
    if (tid == 0) {
        for (int w2 = 1; w2 < 4; ++w2) {
            hp = fmaxf(hp, sb[w2 * 4 + 0]);
            hn = fminf(hn, sb[w2 * 4 + 1]);
            ap = fmaxf(ap, sb[w2 * 4 + 2]);
            an = fmaxf(an, sb[w2 * 4 + 3]);
        }
        // device-scope stores (land at the coherent point, safe across XCDs)
        atomicExch(&php[bid], hp); atomicExch(&phn[bid], hn);
        atomicExch(&pap[bid], ap); atomicExch(&pan[bid], an);
        __threadfence();
        const int t = atomicAdd(cnt, 1);
        isLast = (t == 255);
    }
    __syncthreads();
    if (!isLast) return;

    // ---- final combine (all 256 threads of the last block) ----
    __threadfence();                    // acquire: partials visible
    const int t = tid;
    float fhp = php[t], fhn = phn[t], fap = pap[t], fan = pan[t];
    fhp = fmaxf(fhp, __shfl_down(fhp, 2)); fhp = fmaxf(fhp, __shfl_down(fhp, 1));
    fhn = fminf(fhn, __shfl_down(fhn, 2)); fhn = fminf(fhn, __shfl_down(fhn, 1));
    fap = fmaxf(fap, __shfl_down(fap, 2)); fap = fmaxf(fap, __shfl_down(fap, 1));
    fan = fmaxf(fan, __shfl_down(fan, 2)); fan = fmaxf(fan, __shfl_down(fan, 1));
    __shared__ float fl[64], fc[64];
    if ((t & 3) == 0) {
        const int bb = t >> 2;
        const float valid = (fap > 0.f && fan > 0.f) ? 1.f : 0.f;
        fl[bb] = fmaxf(fhp - fhn + MARGIN, 0.f) * valid;
        fc[bb] = valid;
    }
    __syncthreads();
    if (t < 64) {
        float l = fl[t], c = fc[t];
        #pragma unroll
        for (int off = 32; off > 0; off >>= 1) {
            l += __shfl_down(l, off);
            c += __shfl_down(c, off);
        }
        if (t == 0) out[0] = (c > 0.f) ? (l / c) : 0.f;
    }
}

// ---------------------------------------------------------------------------
extern "C" void kernel_launch(void* const* d_in, const int* in_sizes, int n_in,
                              void* d_out, int out_size, void* d_ws, size_t ws_size,
                              hipStream_t stream) {
    const float* anchor = (const float*)d_in[0];   // (64, 512)
    const float* voxels = (const float*)d_in[1];   // (64, 32768)
    const float* keys   = (const float*)d_in[2];   // (2048, 512)
    const float* vals   = (const float*)d_in[3];   // (2048, 32768)

    float* ws = (float*)d_ws;
    float*  vsqp = ws + OFF_VSQP;
    float*  ainv = ws + OFF_AINV;
    float*  kinv = ws + OFF_KINV;
    float*  wsqp = ws + OFF_WSQP;
    float*  php  = ws + OFF_PHP;
    float*  phn  = ws + OFF_PHN;
    float*  pap  = ws + OFF_PAP;
    float*  pan  = ws + OFF_PAN;
    int*    cnt  = (int*)(ws + OFF_CNT);
    float*  keyp = ws + OFF_KEYP;
    float*  dotp = ws + OFF_DOTP;
    ushort* vhi  = (ushort*)(ws + OFF_VHI);
    ushort* vlo  = (ushort*)(ws + OFF_VLO);

    prep_kernel<<<1040, 256, 0, stream>>>(voxels, anchor, keys, vhi, vlo,
                                          vsqp, ainv, kinv, keyp, cnt);
    gemm_big<<<32 * NS, 256, 0, stream>>>(vhi, vlo, vals, dotp, wsqp);
    rowpart_kernel<<<256, 256, 0, stream>>>(dotp, wsqp, keyp, vsqp, ainv, kinv,
                                            php, phn, pap, pan, cnt, (float*)d_out);
}